// Round 1
// baseline (142.592 us; speedup 1.0000x reference)
//
#include <hip/hip_runtime.h>

#define NPTS 100000
#define NJ 24
#define PDIM 64
#define LL 32
#define CC 16
#define JOINT_STRIDE (PDIM*LL*LL*CC)   /* 1<<20 floats */
#define ID_STRIDE (LL*LL*CC)           /* 16384 floats */
#define RB 100                         /* reduce blocks */

__global__ __launch_bounds__(256) void k_partial(const float* __restrict__ qp,
                                                 float* __restrict__ partial) {
    __shared__ float sm[3][256];
    int tid = threadIdx.x;
    float s0 = 0.f, s1 = 0.f, s2 = 0.f;
    for (int n = blockIdx.x * 256 + tid; n < NPTS; n += RB * 256) {
        s0 += qp[n * 3 + 0];
        s1 += qp[n * 3 + 1];
        s2 += qp[n * 3 + 2];
    }
    sm[0][tid] = s0; sm[1][tid] = s1; sm[2][tid] = s2;
    __syncthreads();
    for (int s = 128; s > 0; s >>= 1) {
        if (tid < s) {
            sm[0][tid] += sm[0][tid + s];
            sm[1][tid] += sm[1][tid + s];
            sm[2][tid] += sm[2][tid + s];
        }
        __syncthreads();
    }
    if (tid == 0) {
        partial[blockIdx.x * 3 + 0] = sm[0][0];
        partial[blockIdx.x * 3 + 1] = sm[1][0];
        partial[blockIdx.x * 3 + 2] = sm[2][0];
    }
}

__global__ __launch_bounds__(256) void k_final(const float* __restrict__ partial,
                                               const float* __restrict__ scale,
                                               float* __restrict__ mi) {
    __shared__ float sm[3][256];
    int tid = threadIdx.x;
    float s0 = 0.f, s1 = 0.f, s2 = 0.f;
    if (tid < RB) {
        s0 = partial[tid * 3 + 0];
        s1 = partial[tid * 3 + 1];
        s2 = partial[tid * 3 + 2];
    }
    sm[0][tid] = s0; sm[1][tid] = s1; sm[2][tid] = s2;
    __syncthreads();
    for (int s = 128; s > 0; s >>= 1) {
        if (tid < s) {
            sm[0][tid] += sm[0][tid + s];
            sm[1][tid] += sm[1][tid + s];
            sm[2][tid] += sm[2][tid + s];
        }
        __syncthreads();
    }
    if (tid == 0) {
        const float invn = 1.0f / (float)NPTS;
        mi[0] = sm[0][0] * invn;
        mi[1] = sm[1][0] * invn;
        mi[2] = sm[2][0] * invn;
        mi[3] = 1.0f / (scale[0] * 0.5f);
        mi[4] = 1.0f / (scale[1] * 0.5f);
        mi[5] = 1.0f / (scale[2] * 0.5f);
    }
}

__device__ __forceinline__ void sample_plane(const float* __restrict__ base,  /* params + id*ID_STRIDE */
                                             float gx, float gy, int jg, int c,
                                             float* __restrict__ outp, int pofs) {
    /* gx indexes W (stride CC), gy indexes H (stride LL*CC) */
    float fx = (gx + 1.0f) * (0.5f * (float)(LL - 1));
    float fy = (gy + 1.0f) * (0.5f * (float)(LL - 1));
    fx = fminf(fmaxf(fx, 0.0f), (float)(LL - 1));
    fy = fminf(fmaxf(fy, 0.0f), (float)(LL - 1));
    int x0 = (int)fx, y0 = (int)fy;
    float wx = fx - (float)x0, wy = fy - (float)y0;
    int x1 = min(x0 + 1, LL - 1), y1 = min(y0 + 1, LL - 1);
    float w00 = (1.f - wx) * (1.f - wy);
    float w01 = wx * (1.f - wy);
    float w10 = (1.f - wx) * wy;
    float w11 = wx * wy;
    int o00 = y0 * (LL * CC) + x0 * CC + c;
    int o01 = y0 * (LL * CC) + x1 * CC + c;
    int o10 = y1 * (LL * CC) + x0 * CC + c;
    int o11 = y1 * (LL * CC) + x1 * CC + c;
#pragma unroll
    for (int jt = 0; jt < 6; ++jt) {
        int j = jt * 4 + jg;
        const float* bj = base + ((size_t)j * JOINT_STRIDE);
        float v = w00 * bj[o00] + w01 * bj[o01] + w10 * bj[o10] + w11 * bj[o11];
        outp[j * (3 * CC) + pofs + c] = v;
    }
}

__global__ __launch_bounds__(256) void k_sample(const float* __restrict__ qp,
                                                const float* __restrict__ px,
                                                const float* __restrict__ py,
                                                const float* __restrict__ pz,
                                                const float* __restrict__ mi,
                                                const int* __restrict__ idp,
                                                float* __restrict__ out) {
    int wave = threadIdx.x >> 6;
    int lane = threadIdx.x & 63;
    int n = blockIdx.x * 4 + wave;
    if (n >= NPTS) return;

    int id = *idp;
    int sid = id * ID_STRIDE;

    float m0 = mi[0], m1 = mi[1], m2 = mi[2];
    float i0 = mi[3], i1 = mi[4], i2 = mi[5];

    float cx = (qp[n * 3 + 0] - m0) * i0;
    float cy = (qp[n * 3 + 1] - m1) * i1;
    float cz = (qp[n * 3 + 2] - m2) * i2;

    int jg = lane >> 4;  /* joint subgroup 0..3 */
    int c  = lane & 15;  /* channel */

    float* outp = out + (size_t)n * (NJ * 3 * CC);

    /* feat_x: gx=y, gy=x; feat_y: gx=z, gy=y; feat_z: gx=x, gy=z */
    sample_plane(px + sid, cy, cx, jg, c, outp, 0);
    sample_plane(py + sid, cz, cy, jg, c, outp, CC);
    sample_plane(pz + sid, cx, cz, jg, c, outp, 2 * CC);
}

extern "C" void kernel_launch(void* const* d_in, const int* in_sizes, int n_in,
                              void* d_out, int out_size, void* d_ws, size_t ws_size,
                              hipStream_t stream) {
    const int*   idp   = (const int*)d_in[0];
    const float* qp    = (const float*)d_in[1];
    const float* scale = (const float*)d_in[2];
    const float* px    = (const float*)d_in[3];
    const float* py    = (const float*)d_in[4];
    const float* pz    = (const float*)d_in[5];
    float* out = (float*)d_out;
    float* ws  = (float*)d_ws;

    /* ws layout: [0,300) partials, [384,390) mean+inv_scale */
    k_partial<<<RB, 256, 0, stream>>>(qp, ws);
    k_final<<<1, 256, 0, stream>>>(ws, scale, ws + 384);
    k_sample<<<(NPTS + 3) / 4, 256, 0, stream>>>(qp, px, py, pz, ws + 384, idp, out);
}